// Round 7
// baseline (135.568 us; speedup 1.0000x reference)
//
#include <hip/hip_runtime.h>
#include <math.h>

// TeacherMLP fused forward.
// R17: split-K eliminated. Thread = (row r = t>>8, neuron o = t&255); each
// thread computes the FULL 256-term tanh-sum for its (r,o): no partial
// arrays, no cross-thread reduction, 3 barriers total (was 7). v2f packs
// adjacent k-pairs (same per-row-term VALU cost as row-pair packing: 33 v2f
// ops per 8 terms). LDS h[4][260] row-major, +4 pad -> rows on disjoint
// banks, wave reads are same-address broadcasts (conflict-free). Weights
// read 4x per block (one per row) -- L1-broadcast, free. Pure C v2f idiom
// (R16-proven, no inline asm -> no miscompile class).
// Theory: R14/R16 calibrate VALU exactly (busy 39us = 8w x 5600 x 2cyc);
// the other ~23us is barrier convoy + split-K LDS round-trips. Removing
// them: mlp 62.3 -> 42-48us, VALUBusy -> 75-85%, bank-conflicts -> ~0.
// If mlp stays ~60: stalls are intrinsic memory latency -> fp16 next.

typedef float v2f __attribute__((ext_vector_type(2)));

#define HCLAMP 12.0f
#define INV2PI 0.15915494309189535f
#define SCW    2.885390081777927f    /* only weff's tanh-atom uses exp2 */
#define LPAD   260                   /* 256 + 4: rows offset by 4 banks */

__device__ __forceinline__ float fast_rcp(float x)  { return __builtin_amdgcn_rcpf(x); }
__device__ __forceinline__ float fast_exp2(float x) { return __builtin_amdgcn_exp2f(x); }
__device__ __forceinline__ v2f pk2(float a, float b) { v2f r; r.x = a; r.y = b; return r; }
__device__ __forceinline__ v2f splat2(float f) { v2f r; r.x = f; r.y = f; return r; }
__device__ __forceinline__ v2f vfma(v2f a, v2f b, v2f c) {
    return __builtin_elementwise_fma(a, b, c);
}

__global__ void weff_kernel(const float* __restrict__ W0, const int* __restrict__ I0,
                            const float* __restrict__ W1, const int* __restrict__ I1,
                            const float* __restrict__ W2, const int* __restrict__ I2,
                            float* __restrict__ ws) {
    int tid = blockIdx.x * blockDim.x + threadIdx.x;   // 0 .. 163839
    const float* W; const int* I; float* out; int outd; int e;
    if (tid < 65536)        { W = W0; I = I0; out = ws;          outd = 256; e = tid; }
    else if (tid < 131072)  { W = W1; I = I1; out = ws + 65536;  outd = 256; e = tid - 65536; }
    else if (tid < 163840)  { W = W2; I = I2; out = ws + 131072; outd = 128; e = tid - 131072; }
    else return;
    int o = e >> 8;       // out index (in-dim always 256)
    int i = e & 255;      // in index
    float w = W[e];       // coalesced (e = o*256 + i)
    int idx = I[e];
    // branchless atoms: [id, sin, tanh, square]
    float sn = __builtin_amdgcn_sinf(w * INV2PI);
    float th = 1.0f - 2.0f * fast_rcp(fast_exp2(w * SCW) + 1.0f);
    float sq = w * w;
    float v = (idx == 1) ? sn : (idx == 2) ? th : (idx == 3) ? sq : w;
    // packed store: [i/4][o][i%4] -> main loop reads float4 of 4 K-values
    out[(i >> 2) * (outd * 4) + o * 4 + (i & 3)] = v;
}

// ---- packed Pade(5,4) tanh as (num, den), pure C vector ops (proven R14/R16):
//      tanh z = z(945+105t+t^2)/(945+420t+15t^2), t=z^2
struct ND { v2f n, d; };
__device__ __forceinline__ ND pade1(v2f z) {
    const v2f c105 = splat2(105.0f), c945 = splat2(945.0f);
    const v2f c420 = splat2(420.0f), c15  = splat2(15.0f);
    v2f t = z * z;
    ND r;
    r.n = z * vfma(t, t + c105, c945);       // z(t^2+105t+945)
    r.d = vfma(t, vfma(t, c15, c420), c945); // 15t^2+420t+945
    return r;
}
__device__ __forceinline__ ND nd_merge(ND a, ND b) {
    ND r;
    r.n = vfma(a.n, b.d, b.n * a.d);
    r.d = a.d * b.d;
    return r;
}
// merge two 4-term NDs (8 terms) with ONE rcp pair; den8 <= 2.8e4^8 = 3.8e35 ok.
__device__ __forceinline__ v2f sig8_acc(ND a, ND b, v2f acc) {
    v2f num = vfma(b.n, a.d, a.n * b.d);
    v2f den = a.d * b.d;
    v2f rd;  rd.x = fast_rcp(den.x); rd.y = fast_rcp(den.y);
    return vfma(num, rd, acc);
}

__global__ __launch_bounds__(1024, 2) void mlp_kernel(
    const float* __restrict__ x,  const float* __restrict__ b0,
    const float* __restrict__ b1, const float* __restrict__ b2,
    const float* __restrict__ ws, float* __restrict__ out) {
    const float4* We0 = (const float4*)ws;             // [64][256] packed [k/4][o][k%4]
    const float4* We1 = (const float4*)(ws + 65536);   // [64][256]
    const float4* We2 = (const float4*)(ws + 131072);  // [64][128]

    __shared__ __align__(16) float hA[4 * LPAD];   // [row][260], 16B-aligned rows
    __shared__ __align__(16) float hB[4 * LPAD];

    const int t = threadIdx.x;     // 0..1023
    const int r = t >> 8;          // row 0..3 (wave-uniform)
    const int o = t & 255;         // neuron
    const int row0 = blockIdx.x * 4;

    // stage: thread (r,o) loads x[row0+r][o]
    {
        float xv = x[(row0 + r) * 256 + o];
        hA[r * LPAD + o] = fminf(fmaxf(xv, -HCLAMP), HCLAMP);
    }
    __syncthreads();

    // ---------------- layer 0: hA -> hB ----------------
    {
        const float bias = b0[o];
        const float* hr = hA + r * LPAD;
        v2f acc = splat2(0.f);
#pragma unroll 2
        for (int kk = 0; kk < 64; kk += 2) {       // 8 k-terms per iter
            float4 w0v = We0[kk * 256 + o];        // k = 4kk .. 4kk+3
            float4 w1v = We0[(kk + 1) * 256 + o];  // k = 4kk+4 .. 4kk+7
            float4 h0v = *(const float4*)(hr + kk * 4);
            float4 h1v = *(const float4*)(hr + kk * 4 + 4);
            ND a = nd_merge(pade1(pk2(h0v.x, h0v.y) * pk2(w0v.x, w0v.y)),
                            pade1(pk2(h0v.z, h0v.w) * pk2(w0v.z, w0v.w)));
            ND b = nd_merge(pade1(pk2(h1v.x, h1v.y) * pk2(w1v.x, w1v.y)),
                            pade1(pk2(h1v.z, h1v.w) * pk2(w1v.z, w1v.w)));
            acc = sig8_acc(a, b, acc);
        }
        float h = acc.x + acc.y + bias;
        h = fminf(fmaxf(h, -HCLAMP), HCLAMP);
        hB[r * LPAD + o] = h;    // distinct buffer: no WAR with hA readers
    }
    __syncthreads();

    // ---------------- layer 1: hB -> hA ----------------
    {
        const float bias = b1[o];
        const float* hr = hB + r * LPAD;
        v2f acc = splat2(0.f);
#pragma unroll 2
        for (int kk = 0; kk < 64; kk += 2) {
            float4 w0v = We1[kk * 256 + o];
            float4 w1v = We1[(kk + 1) * 256 + o];
            float4 h0v = *(const float4*)(hr + kk * 4);
            float4 h1v = *(const float4*)(hr + kk * 4 + 4);
            ND a = nd_merge(pade1(pk2(h0v.x, h0v.y) * pk2(w0v.x, w0v.y)),
                            pade1(pk2(h0v.z, h0v.w) * pk2(w0v.z, w0v.w)));
            ND b = nd_merge(pade1(pk2(h1v.x, h1v.y) * pk2(w1v.x, w1v.y)),
                            pade1(pk2(h1v.z, h1v.w) * pk2(w1v.z, w1v.w)));
            acc = sig8_acc(a, b, acc);
        }
        float h = acc.x + acc.y + bias;
        h = fminf(fmaxf(h, -HCLAMP), HCLAMP);
        hA[r * LPAD + o] = h;    // hA reads all finished before prior barrier
    }
    __syncthreads();

    // ---------------- layer 2: hA -> out (plain dot, no tanh) ----------------
    if (o < 128) {               // wave-uniform: waves 2,3 of each row idle
        const float* hr = hA + r * LPAD;
        v2f acc = splat2(0.f);
#pragma unroll 4
        for (int kk = 0; kk < 64; kk++) {
            float4 w = We2[kk * 128 + o];
            float4 h = *(const float4*)(hr + kk * 4);
            acc = vfma(pk2(h.x, h.y), pk2(w.x, w.y), acc);
            acc = vfma(pk2(h.z, h.w), pk2(w.z, w.w), acc);
        }
        out[(row0 + r) * 128 + o] = acc.x + acc.y + b2[o];
    }
}

extern "C" void kernel_launch(void* const* d_in, const int* in_sizes, int n_in,
                              void* d_out, int out_size, void* d_ws, size_t ws_size,
                              hipStream_t stream) {
    const float* x  = (const float*)d_in[0];
    const float* W0 = (const float*)d_in[1];
    const float* b0 = (const float*)d_in[2];
    const int*   I0 = (const int*)  d_in[3];
    const float* W1 = (const float*)d_in[4];
    const float* b1 = (const float*)d_in[5];
    const int*   I1 = (const int*)  d_in[6];
    const float* W2 = (const float*)d_in[7];
    const float* b2 = (const float*)d_in[8];
    const int*   I2 = (const int*)  d_in[9];
    float* ws  = (float*)d_ws;    // 163840 floats = 655360 B
    float* out = (float*)d_out;

    weff_kernel<<<640, 256, 0, stream>>>(W0, I0, W1, I1, W2, I2, ws);
    mlp_kernel<<<512, 1024, 0, stream>>>(x, b0, b1, b2, ws, out);
}

// Round 8
// 115.360 us; speedup vs baseline: 1.1752x; 1.1752x over previous
//
#include <hip/hip_runtime.h>
#include <math.h>

// TeacherMLP fused forward.
// R18 = R12's exact skeleton+math (exp2-based tanh via B=2^-8(e^{2z}+1),
// split-K/4, two packed row-pairs, partials+7 barriers -- passed twice at
// mlp ~51-53us) with two changes:
//  (1) all inline asm replaced by compiler v2f ops (R16 proved parity+safety;
//      kills the R9/R11/R13/R15 miscompile class),
//  (2) full unroll of the 8-trip hidden loops and layer-2 loop (LDS reads
//      become offset-immediates, weight addresses fold to SGPR adds).
// Theory: across R12/R14/R16/R17, dur = VALU_busy/0.63 invariably (waves,
// barriers, conflicts all ruled out). Minimize busy: exp2 math has the
// lowest busy (33us, trans pipe runs parallel and balanced), and ~half of
// issued instrs are loop/addr overhead that unrolling removes.
// Prediction: pass; mlp 62.3 -> 40-50us (busy 33 -> 24-29); worst case
// parity with R12 ~52; VGPR 80-128 ok (4 waves/SIMD proven perf-neutral).

typedef float v2f __attribute__((ext_vector_type(2)));

#define SC   2.885390081777927f      /* 2*log2(e): exp2(SC*z) = e^{2z} */
#define INV  (1.0f / 2.885390081777927f)
#define INV2PI 0.15915494309189535f
#define HS_CLAMP 32.0f               /* clamp on SC-prescaled activations */
#define C8   0.00390625f             /* 2^-8 */

__device__ __forceinline__ float fast_rcp(float x)  { return __builtin_amdgcn_rcpf(x); }
__device__ __forceinline__ float fast_exp2(float x) { return __builtin_amdgcn_exp2f(x); }
__device__ __forceinline__ v2f pk2(float a, float b) { v2f r; r.x = a; r.y = b; return r; }
__device__ __forceinline__ v2f splat2(float f) { v2f r; r.x = f; r.y = f; return r; }
__device__ __forceinline__ v2f vfma(v2f a, v2f b, v2f c) {
    return __builtin_elementwise_fma(a, b, c);
}
__device__ __forceinline__ v2f pexp(v2f t) {  // 2 HW exp2 (trans pipe)
    v2f e; e.x = fast_exp2(t.x); e.y = fast_exp2(t.y); return e;
}

__global__ void weff_kernel(const float* __restrict__ W0, const int* __restrict__ I0,
                            const float* __restrict__ W1, const int* __restrict__ I1,
                            const float* __restrict__ W2, const int* __restrict__ I2,
                            float* __restrict__ ws) {
    int tid = blockIdx.x * blockDim.x + threadIdx.x;   // 0 .. 163839
    const float* W; const int* I; float* out; int outd; int e;
    if (tid < 65536)        { W = W0; I = I0; out = ws;          outd = 256; e = tid; }
    else if (tid < 131072)  { W = W1; I = I1; out = ws + 65536;  outd = 256; e = tid - 65536; }
    else if (tid < 163840)  { W = W2; I = I2; out = ws + 131072; outd = 128; e = tid - 131072; }
    else return;
    int o = e >> 8;       // out index (in-dim always 256)
    int i = e & 255;      // in index
    float w = W[e];       // coalesced (e = o*256 + i)
    int idx = I[e];
    // branchless atoms: [id, sin, tanh, square]
    float sn = __builtin_amdgcn_sinf(w * INV2PI);
    float th = 1.0f - 2.0f * fast_rcp(fast_exp2(w * SC) + 1.0f);
    float sq = w * w;
    float v = (idx == 1) ? sn : (idx == 2) ? th : (idx == 3) ? sq : w;
    // packed store: [i/4][o][i%4] -> main loop reads float4 of 4 K-values
    out[(i >> 2) * (outd * 4) + o * 4 + (i & 3)] = v;
}

// num/den of sum_{k=0..3} 1/B_k over 4 i-values, one row-pair packed.
// B = exp2(t-8) + 2^-8 = 2^-8 * (e^{2z}+1); shift folds into the t-fma.
struct ND { v2f n, d; };
__device__ __forceinline__ ND tree4(float4 pa, float4 pb, float4 w, v2f m8, v2f c8) {
    v2f B0 = pexp(vfma(pk2(pa.x, pa.y), splat2(w.x), m8)) + c8;
    v2f B1 = pexp(vfma(pk2(pa.z, pa.w), splat2(w.y), m8)) + c8;
    v2f B2 = pexp(vfma(pk2(pb.x, pb.y), splat2(w.z), m8)) + c8;
    v2f B3 = pexp(vfma(pk2(pb.z, pb.w), splat2(w.w), m8)) + c8;
    v2f S1 = B0 + B1, P1 = B0 * B1;
    v2f S2 = B2 + B3, P2 = B2 * B3;
    ND r;
    r.n = vfma(S2, P1, S1 * P2);
    r.d = P1 * P2;
    return r;
}

// merge two 4-trees (8 sigma-terms, one row-pair) with ONE rcp per row.
__device__ __forceinline__ v2f sig8_acc(ND a, ND b, v2f acc) {
    v2f num = vfma(b.n, a.d, a.n * b.d);
    v2f den = a.d * b.d;
    v2f rd;  rd.x = fast_rcp(den.x); rd.y = fast_rcp(den.y);
    return vfma(num, rd, acc);
}

__global__ __launch_bounds__(1024, 4) void mlp_kernel(
    const float* __restrict__ x,  const float* __restrict__ b0,
    const float* __restrict__ b1, const float* __restrict__ b2,
    const float* __restrict__ ws, float* __restrict__ out) {
    const float4* We0 = (const float4*)ws;             // [64][256] packed [ic][o][4]
    const float4* We1 = (const float4*)(ws + 65536);   // [64][256]
    const float4* We2 = (const float4*)(ws + 131072);  // [64][128]

    __shared__ __align__(16) v2f hA0[256];      // pair0: rows (row0, row0+1)
    __shared__ __align__(16) v2f hA1[256];      // pair1: rows (row0+2, row0+3)
    __shared__ __align__(16) v2f hB0[256];
    __shared__ __align__(16) v2f hB1[256];
    __shared__ __align__(16) v2f partA[1024];   // split-K partials, pair 0
    __shared__ __align__(16) v2f partB[1024];   // pair 1

    const int t = threadIdx.x;     // 0..1023
    const int g = t >> 8;          // K-group 0..3 (wave-uniform)
    const int o = t & 255;         // neuron
    const int p = g >> 1;          // pair select (staging/epilogue role)
    const int l = g & 1;           // lane within pair
    const int row0 = blockIdx.x * 4;

    const v2f m8 = pk2(-8.0f, -8.0f);
    const v2f c8 = pk2(C8, C8);

    // stage 4 input rows: thread (g,o) stages row row0+2p+l, column o.
    {
        float xv = x[(row0 + 2 * p + l) * 256 + o] * SC;
        xv = fminf(fmaxf(xv, -HS_CLAMP), HS_CLAMP);
        ((float*)((p ? hA1 : hA0) + o))[l] = xv;
    }
    __syncthreads();

    // ---------------- layer 0: hA* -> hB* ----------------
    {
        const float bias = b0[o];
        v2f acc0 = splat2(0.f), acc1 = splat2(0.f);
#pragma unroll
        for (int icc = 0; icc < 16; icc += 2) {
            int ic = g * 16 + icc;
            float4 w0 = We0[ic * 256 + o];
            float4 w1 = We0[(ic + 1) * 256 + o];
            const float4* hp0 = (const float4*)(hA0 + ic * 4);
            const float4* hp1 = (const float4*)(hA1 + ic * 4);
            ND r0 = tree4(hp0[0], hp0[1], w0, m8, c8);
            ND r1 = tree4(hp0[2], hp0[3], w1, m8, c8);
            acc0 = sig8_acc(r0, r1, acc0);
            ND r2 = tree4(hp1[0], hp1[1], w0, m8, c8);   // independent chain
            ND r3 = tree4(hp1[2], hp1[3], w1, m8, c8);
            acc1 = sig8_acc(r2, r3, acc1);
        }
        partA[g * 256 + o] = acc0;
        partB[g * 256 + o] = acc1;
        __syncthreads();
        const v2f* prt = p ? partB : partA;
        float s = ((const float*)(prt + o))[l]
                + ((const float*)(prt + 256 + o))[l]
                + ((const float*)(prt + 512 + o))[l]
                + ((const float*)(prt + 768 + o))[l];
        float h = (256.0f - 0.0078125f * s + bias) * SC;   // 2^-7 undoes B-scale x2
        h = fminf(fmaxf(h, -HS_CLAMP), HS_CLAMP);
        ((float*)((p ? hB1 : hB0) + o))[l] = h;
        __syncthreads();
    }

    // ---------------- layer 1: hB* -> (hA0, hB1) ----------------
    {
        const float bias = b1[o];
        v2f acc0 = splat2(0.f), acc1 = splat2(0.f);
#pragma unroll
        for (int icc = 0; icc < 16; icc += 2) {
            int ic = g * 16 + icc;
            float4 w0 = We1[ic * 256 + o];
            float4 w1 = We1[(ic + 1) * 256 + o];
            const float4* hp0 = (const float4*)(hB0 + ic * 4);
            const float4* hp1 = (const float4*)(hB1 + ic * 4);
            ND r0 = tree4(hp0[0], hp0[1], w0, m8, c8);
            ND r1 = tree4(hp0[2], hp0[3], w1, m8, c8);
            acc0 = sig8_acc(r0, r1, acc0);
            ND r2 = tree4(hp1[0], hp1[1], w0, m8, c8);
            ND r3 = tree4(hp1[2], hp1[3], w1, m8, c8);
            acc1 = sig8_acc(r2, r3, acc1);
        }
        partA[g * 256 + o] = acc0;
        partB[g * 256 + o] = acc1;
        __syncthreads();
        const v2f* prt = p ? partB : partA;
        float s = ((const float*)(prt + o))[l]
                + ((const float*)(prt + 256 + o))[l]
                + ((const float*)(prt + 512 + o))[l]
                + ((const float*)(prt + 768 + o))[l];
        float h = (256.0f - 0.0078125f * s + bias) * SC;
        h = fminf(fmaxf(h, -HS_CLAMP), HS_CLAMP);
        // pair0 -> hA0, pair1 -> hB1 (hB1's inner-loop reads completed before
        // the barrier above; hA1 stays untouched to avoid any WAR surprise).
        ((float*)((p ? hB1 : hA0) + o))[l] = h;
        __syncthreads();
    }

    // ---------------- layer 2: (hA0 pair0, hB1 pair1) -> out ----------------
    {
        const int o2 = t & 127;
        const int q  = t >> 7;     // K-eighth 0..7
        v2f acc0 = splat2(0.f), acc1 = splat2(0.f);
#pragma unroll
        for (int icc = 0; icc < 8; icc++) {
            int ic = q * 8 + icc;
            float4 w = We2[ic * 128 + o2];
            const float4* hp0 = (const float4*)(hA0 + ic * 4);
            const float4* hp1 = (const float4*)(hB1 + ic * 4);
            float4 pa = hp0[0], pb = hp0[1];
            float4 qa = hp1[0], qb = hp1[1];
            acc0 = vfma(pk2(pa.x, pa.y), splat2(w.x), acc0);
            acc0 = vfma(pk2(pa.z, pa.w), splat2(w.y), acc0);
            acc0 = vfma(pk2(pb.x, pb.y), splat2(w.z), acc0);
            acc0 = vfma(pk2(pb.z, pb.w), splat2(w.w), acc0);
            acc1 = vfma(pk2(qa.x, qa.y), splat2(w.x), acc1);
            acc1 = vfma(pk2(qa.z, qa.w), splat2(w.y), acc1);
            acc1 = vfma(pk2(qb.x, qb.y), splat2(w.z), acc1);
            acc1 = vfma(pk2(qb.z, qb.w), splat2(w.w), acc1);
        }
        partA[q * 128 + o2] = acc0;
        partB[q * 128 + o2] = acc1;
        __syncthreads();
        // 512 outputs (4 rows x 128), one per thread in the first half-block.
        if (t < 512) {
            const int r  = t >> 7;        // 0..3 -> row row0 + r
            const int oo = t & 127;
            const v2f* prt = (r & 2) ? partB : partA;
            const int  ln  = r & 1;
            float s = 0.0f;
#pragma unroll
            for (int q2 = 0; q2 < 8; q2++)
                s += ((const float*)(prt + q2 * 128 + oo))[ln];
            out[(row0 + r) * 128 + oo] = s * INV + b2[oo];  // undo SC prescale
        }
    }
}

extern "C" void kernel_launch(void* const* d_in, const int* in_sizes, int n_in,
                              void* d_out, int out_size, void* d_ws, size_t ws_size,
                              hipStream_t stream) {
    const float* x  = (const float*)d_in[0];
    const float* W0 = (const float*)d_in[1];
    const float* b0 = (const float*)d_in[2];
    const int*   I0 = (const int*)  d_in[3];
    const float* W1 = (const float*)d_in[4];
    const float* b1 = (const float*)d_in[5];
    const int*   I1 = (const int*)  d_in[6];
    const float* W2 = (const float*)d_in[7];
    const float* b2 = (const float*)d_in[8];
    const int*   I2 = (const int*)  d_in[9];
    float* ws  = (float*)d_ws;    // 163840 floats = 655360 B
    float* out = (float*)d_out;

    weff_kernel<<<640, 256, 0, stream>>>(W0, I0, W1, I1, W2, I2, ws);
    mlp_kernel<<<512, 1024, 0, stream>>>(x, b0, b1, b2, ws, out);
}